// Round 2
// baseline (236.828 us; speedup 1.0000x reference)
//
#include <hip/hip_runtime.h>
#include <math.h>

#define NTOK   16384
#define DIM    2048
#define NEXP   64
#define TOPK   8
#define TB     32          // tokens per block
#define KC     128         // K chunk
#define NCHUNK (DIM / KC)  // 16
#define PS_STRIDE 129      // +1 pad -> 2-way (free) LDS bank pattern

// ---------------- kernel 1: per-expert inverse norms (f64) ----------------
__global__ __launch_bounds__(64) void proto_norm_kernel(
    const float* __restrict__ proto, double* __restrict__ pinv)
{
    const int e = blockIdx.x;
    const int lane = threadIdx.x;
    const float* row = proto + e * DIM;
    double s = 0.0;
#pragma unroll
    for (int i = 0; i < DIM / 64; ++i) {
        float v = row[lane + 64 * i];
        s += (double)v * (double)v;
    }
#pragma unroll
    for (int d = 1; d < 64; d <<= 1)
        s += __shfl_xor(s, d, 64);
    if (lane == 0)
        pinv[e] = 1.0 / fmax(sqrt(s), 1e-12);
}

// ---------------- kernel 2: fused cosine-logits + fp32 softmax + top-k ----------------
__global__ __launch_bounds__(256, 2) void router_kernel(
    const float* __restrict__ x, const float* __restrict__ proto,
    const double* __restrict__ pinv, float* __restrict__ out)
{
    __shared__ float  ps[NEXP * PS_STRIDE];  // 33024 B, proto chunk [e][k]
    __shared__ float  xs[TB * KC];           // 16384 B, token chunk [t][k]
    __shared__ double xinv[TB];              // 256 B

    const int tid  = threadIdx.x;
    const int lane = tid & 63;               // lane == expert id
    const int w    = tid >> 6;               // wave id 0..3
    const int tok0 = blockIdx.x * TB;

    const double pe = pinv[lane];            // per-expert inverse norm

    double acc[8];
#pragma unroll
    for (int i = 0; i < 8; ++i) acc[i] = 0.0;
    double slot[4] = {0.0, 0.0, 0.0, 0.0};   // token sumsq partials

    const float4* pg = (const float4*)proto;
    const float4* xg = (const float4*)x;

    for (int kc = 0; kc < NCHUNK; ++kc) {
        __syncthreads();
        // stage proto chunk: 64 rows x 128 floats = 2048 float4s
#pragma unroll
        for (int it = 0; it < 8; ++it) {
            int idx = tid + it * 256;
            int e = idx >> 5, c4 = idx & 31;
            float4 v = pg[e * (DIM / 4) + kc * (KC / 4) + c4];
            float* dst = &ps[e * PS_STRIDE + c4 * 4];
            dst[0] = v.x; dst[1] = v.y; dst[2] = v.z; dst[3] = v.w;
        }
        // stage x chunk: 32 rows x 128 floats = 1024 float4s; fuse sumsq
#pragma unroll
        for (int it = 0; it < 4; ++it) {
            int idx = tid + it * 256;
            int r = idx >> 5, c4 = idx & 31;
            float4 v = xg[(size_t)(tok0 + r) * (DIM / 4) + kc * (KC / 4) + c4];
            *(float4*)&xs[r * KC + c4 * 4] = v;
            slot[it] += (double)v.x * v.x + (double)v.y * v.y +
                        (double)v.z * v.z + (double)v.w * v.w;
        }
        __syncthreads();
        // compute: lane = expert, wave's 8 tokens, f64 accumulate
#pragma unroll 1
        for (int k0 = 0; k0 < KC; k0 += 8) {
            float p[8];
#pragma unroll
            for (int j = 0; j < 8; ++j)
                p[j] = ps[lane * PS_STRIDE + k0 + j];  // 2-way, free
#pragma unroll
            for (int i = 0; i < 8; ++i) {
                const float* xr = &xs[(w * 8 + i) * KC + k0];
                float4 a0 = *(const float4*)xr;        // uniform addr -> broadcast
                float4 a1 = *(const float4*)(xr + 4);
                acc[i] += (double)a0.x * p[0];
                acc[i] += (double)a0.y * p[1];
                acc[i] += (double)a0.z * p[2];
                acc[i] += (double)a0.w * p[3];
                acc[i] += (double)a1.x * p[4];
                acc[i] += (double)a1.y * p[5];
                acc[i] += (double)a1.z * p[6];
                acc[i] += (double)a1.w * p[7];
            }
        }
    }

    // token inverse norms: slot[it] belongs to token 8*it + (tid>>5);
    // reduce across the 32 contiguous threads sharing tid>>5 (half-wave)
#pragma unroll
    for (int it = 0; it < 4; ++it) {
        double s = slot[it];
#pragma unroll
        for (int d = 1; d < 32; d <<= 1)
            s += __shfl_down(s, d, 32);
        if ((tid & 31) == 0)
            xinv[8 * it + (tid >> 5)] = 1.0 / fmax(sqrt(s), 1e-12);
    }
    __syncthreads();

    // epilogue: per token -> replicate np's fp32 softmax bit-chain, rank by (w32, idx)
#pragma unroll 1
    for (int i = 0; i < 8; ++i) {
        const int t = w * 8 + i;
        const double v64 = acc[i] * xinv[t] * pe;  // near-exact fp64 cosine logit
        const float l32 = (float)v64;              // the reference's astype(float32)

        // fp32 wave max (exact, order-free)
        float m = l32;
#pragma unroll
        for (int d = 1; d < 64; d <<= 1) {
            float o = __shfl_xor(m, d, 64);
            m = fmaxf(m, o);
        }
        // fp32 exp, correctly rounded via fp64
        const float dd = l32 - m;                  // IEEE fp32 subtract
        const float e32 = (float)exp((double)dd);

        // numpy pairwise_sum (n=64): 8 scalar accumulators over stride 8,
        // combined ((r0+r1)+(r2+r3))+((r4+r5)+(r6+r7)); broadcast shuffles
        float r[8];
#pragma unroll
        for (int j = 0; j < 8; ++j) {
            float rj = __shfl(e32, j, 64);
#pragma unroll
            for (int b = 1; b < 8; ++b)
                rj += __shfl(e32, j + 8 * b, 64);
            r[j] = rj;
        }
        const float S = ((r[0] + r[1]) + (r[2] + r[3])) +
                        ((r[4] + r[5]) + (r[6] + r[7]));
        const float wgt = e32 / S;                 // IEEE fp32 divide

        // rank by (w32 desc, index asc) — replicates stable top-k on fp32 weights
        int rank = 0;
#pragma unroll 1
        for (int sdist = 1; sdist < 64; ++sdist) {
            float ow = __shfl_xor(wgt, sdist, 64);
            int j = lane ^ sdist;
            rank += (ow > wgt) || (ow == wgt && j < lane);
        }

        if (rank < TOPK) {
            int tok = tok0 + t;
            out[tok * TOPK + rank] = wgt;                       // routing_weights
            out[NTOK * TOPK + tok * TOPK + rank] = (float)lane; // selected_experts
        }
    }
}

extern "C" void kernel_launch(void* const* d_in, const int* in_sizes, int n_in,
                              void* d_out, int out_size, void* d_ws, size_t ws_size,
                              hipStream_t stream) {
    const float* x     = (const float*)d_in[0];
    const float* proto = (const float*)d_in[1];
    float* out         = (float*)d_out;
    double* pinv       = (double*)d_ws;  // 64 doubles

    proto_norm_kernel<<<NEXP, 64, 0, stream>>>(proto, pinv);
    router_kernel<<<NTOK / TB, 256, 0, stream>>>(x, proto, pinv, out);
}

// Round 4
// 158.621 us; speedup vs baseline: 1.4930x; 1.4930x over previous
//
#include <hip/hip_runtime.h>
#include <math.h>

#define NTOK   16384
#define DIM    2048
#define NEXP   64
#define TOPK   8
#define TB     32          // tokens per block
#define KC     64          // K chunk
#define NCHUNK (DIM / KC)  // 32
#define XP     66          // padded row stride (doubles), keeps 16B alignment
#define PP     66

typedef double v4d __attribute__((ext_vector_type(4)));
typedef double v2d __attribute__((ext_vector_type(2)));

// ---------------- kernel 1: per-expert inverse norms (f64) ----------------
__global__ __launch_bounds__(64) void proto_norm_kernel(
    const float* __restrict__ proto, double* __restrict__ pinv)
{
    const int e = blockIdx.x;
    const int lane = threadIdx.x;
    const float* row = proto + e * DIM;
    double s = 0.0;
#pragma unroll
    for (int i = 0; i < DIM / 64; ++i) {
        float v = row[lane + 64 * i];
        s += (double)v * (double)v;
    }
#pragma unroll
    for (int d = 1; d < 64; d <<= 1)
        s += __shfl_xor(s, d, 64);
    if (lane == 0)
        pinv[e] = 1.0 / fmax(sqrt(s), 1e-12);
}

// ---------------- kernel 2: f64-MFMA logits (self-calibrating layout) ----------------
__global__ __launch_bounds__(256, 2) void router_kernel(
    const float* __restrict__ x, const float* __restrict__ proto,
    const double* __restrict__ pinv, float* __restrict__ out)
{
    __shared__ double p_lds[NEXP][PP];   // 33792 B, row-major [e][k]
    __shared__ double x_lds[TB][XP];     // 16896 B, row-major [t][k]
    __shared__ double xinv_lds[TB];
    __shared__ double pinv_lds[NEXP];
    float* logits = reinterpret_cast<float*>(&x_lds[0][0]);  // [TB][NEXP] f32, reused

    const int tid  = threadIdx.x;
    const int lane = tid & 63;
    const int w    = tid >> 6;               // wave 0..3
    const int tok0 = blockIdx.x * TB;

    // staging assignment
    const int sx_t = tid >> 3;               // token 0..31 (8 thr/token)
    const int sx_k = (tid & 7) * 8;          // 8 floats each
    const int sp_e = tid >> 2;               // expert 0..63 (4 thr/expert)
    const int sp_k = (tid & 3) * 16;         // 16 floats each

    // MFMA tile assignment: 2 t-tiles x 2 e-pairs, 1 (t,epair) per wave
    const int ttile = w & 1;
    const int epair = w >> 1;
    const int arow  = lane & 15;             // my A-row / B-col label
    const int akg   = lane >> 4;             // my k label (irrelevant to result)

    if (tid < NEXP) pinv_lds[tid] = pinv[tid];

    // ---- layout calibration: discover true (lane,reg) -> (row,col) mapping ----
    v4d c1 = {0.0, 0.0, 0.0, 0.0};
    v4d c2 = {0.0, 0.0, 0.0, 0.0};
    c1 = __builtin_amdgcn_mfma_f64_16x16x4f64((double)arow, 1.0, c1, 0, 0, 0);
    c2 = __builtin_amdgcn_mfma_f64_16x16x4f64(1.0, (double)arow, c2, 0, 0, 0);

    v4d acc0 = {0.0, 0.0, 0.0, 0.0};
    v4d acc1 = {0.0, 0.0, 0.0, 0.0};
    double sumsq = 0.0;

    for (int c = 0; c < NCHUNK; ++c) {
        __syncthreads();
        // ---- stage x chunk: 8 floats -> f64 row-major; fuse token sumsq ----
        {
            const float* src = x + (size_t)(tok0 + sx_t) * DIM + c * KC + sx_k;
            float4 v0 = *(const float4*)src;
            float4 v1 = *(const float4*)(src + 4);
            double d0 = (double)v0.x, d1 = (double)v0.y,
                   d2 = (double)v0.z, d3 = (double)v0.w;
            double d4 = (double)v1.x, d5 = (double)v1.y,
                   d6 = (double)v1.z, d7 = (double)v1.w;
            v2d* dst = (v2d*)&x_lds[sx_t][sx_k];
            dst[0] = (v2d){d0, d1};
            dst[1] = (v2d){d2, d3};
            dst[2] = (v2d){d4, d5};
            dst[3] = (v2d){d6, d7};
            sumsq += d0 * d0 + d1 * d1 + d2 * d2 + d3 * d3 +
                     d4 * d4 + d5 * d5 + d6 * d6 + d7 * d7;
        }
        // ---- stage proto chunk: 16 floats -> f64 row-major ----
        {
            const float* src = proto + (size_t)sp_e * DIM + c * KC + sp_k;
            v2d* dst = (v2d*)&p_lds[sp_e][sp_k];
#pragma unroll
            for (int q = 0; q < 4; ++q) {
                float4 v = *(const float4*)(src + 4 * q);
                dst[2 * q + 0] = (v2d){(double)v.x, (double)v.y};
                dst[2 * q + 1] = (v2d){(double)v.z, (double)v.w};
            }
        }
        __syncthreads();
        // ---- compute: 16 MFMA K-steps, 2 e-tiles per wave ----
#pragma unroll
        for (int ks = 0; ks < KC / 4; ++ks) {
            const int k = ks * 4 + akg;
            double a  = x_lds[ttile * 16 + arow][k];
            double b0 = p_lds[epair * 32 + arow][k];
            double b1 = p_lds[epair * 32 + 16 + arow][k];
            acc0 = __builtin_amdgcn_mfma_f64_16x16x4f64(a, b0, acc0, 0, 0, 0);
            acc1 = __builtin_amdgcn_mfma_f64_16x16x4f64(a, b1, acc1, 0, 0, 0);
        }
    }

    // ---- token inverse norms: reduce 8 consecutive threads per token ----
    {
        double s = sumsq;
#pragma unroll
        for (int d = 1; d < 8; d <<= 1)
            s += __shfl_down(s, d, 8);
        if ((tid & 7) == 0)
            xinv_lds[sx_t] = 1.0 / fmax(sqrt(s), 1e-12);
    }
    __syncthreads();   // also guards: all MFMA LDS reads done before logits alias-write

    // ---- scale to cosine logits using calibrated labels, cast fp32, reshard ----
#pragma unroll
    for (int i = 0; i < 4; ++i) {
        const int tr = (int)(c1[i] * 0.25);      // true token-within-tile label
        const int ec = (int)(c2[i] * 0.25);      // true expert-within-16 label
        const int tl = ttile * 16 + tr;
        const double xi = xinv_lds[tl];
        const int e0 = epair * 32 + ec;
        const int e1 = epair * 32 + 16 + ec;
        logits[tl * NEXP + e0] = (float)(acc0[i] * xi * pinv_lds[e0]);
        logits[tl * NEXP + e1] = (float)(acc1[i] * xi * pinv_lds[e1]);
    }
    __syncthreads();

    // ---- epilogue: np fp32 softmax bit-chain + rank by (w32 desc, idx asc) ----
#pragma unroll 1
    for (int i = 0; i < 8; ++i) {
        const int tl = w * 8 + i;
        const float l32 = logits[tl * NEXP + lane];

        float m = l32;
#pragma unroll
        for (int d = 1; d < 64; d <<= 1) {
            float o = __shfl_xor(m, d, 64);
            m = fmaxf(m, o);
        }
        const float dd = l32 - m;
        const float e32 = (float)exp((double)dd);

        // numpy pairwise_sum (n=64): 8 accumulators over stride 8
        float r[8];
#pragma unroll
        for (int j = 0; j < 8; ++j) {
            float rj = __shfl(e32, j, 64);
#pragma unroll
            for (int b = 1; b < 8; ++b)
                rj += __shfl(e32, j + 8 * b, 64);
            r[j] = rj;
        }
        const float S = ((r[0] + r[1]) + (r[2] + r[3])) +
                        ((r[4] + r[5]) + (r[6] + r[7]));
        const float wgt = e32 / S;

        int rank = 0;
#pragma unroll 1
        for (int sdist = 1; sdist < 64; ++sdist) {
            float ow = __shfl_xor(wgt, sdist, 64);
            int j = lane ^ sdist;
            rank += (ow > wgt) || (ow == wgt && j < lane);
        }

        if (rank < TOPK) {
            const int tok = tok0 + tl;
            out[tok * TOPK + rank] = wgt;                       // routing_weights
            out[NTOK * TOPK + tok * TOPK + rank] = (float)lane; // selected_experts
        }
    }
}

extern "C" void kernel_launch(void* const* d_in, const int* in_sizes, int n_in,
                              void* d_out, int out_size, void* d_ws, size_t ws_size,
                              hipStream_t stream) {
    const float* x     = (const float*)d_in[0];
    const float* proto = (const float*)d_in[1];
    float* out         = (float*)d_out;
    double* pinv       = (double*)d_ws;  // 64 doubles

    proto_norm_kernel<<<NEXP, 64, 0, stream>>>(proto, pinv);
    router_kernel<<<NTOK / TB, 256, 0, stream>>>(x, proto, pinv, out);
}